// Round 14
// baseline (236.492 us; speedup 1.0000x reference)
//
#include <hip/hip_runtime.h>
#include <hip/hip_bf16.h>

// Round 14: r13 + GEMM3 fused into L2's epilogue (h2 never leaves the block:
// registers -> swizzled LDS chunks -> MFMA with W3 -> eo). Deletes the gemm3
// dispatch and the 35MB h2 round-trip.
#define N_TOK 16384
#define MAX_SLOTS 34080
#define MAX_BLOCKS 216

typedef __attribute__((ext_vector_type(8))) short bf16x8;
typedef __attribute__((ext_vector_type(4))) float f32x4;
typedef unsigned short u16;

__device__ __forceinline__ u16 f2bf(float f) {
  __hip_bfloat16 h = __float2bfloat16(f);
  union { __hip_bfloat16 b; u16 u; } c; c.b = h; return c.u;
}
__device__ __forceinline__ float bfbits2f(u16 u) {
  return __uint_as_float(((unsigned)u) << 16);
}
__device__ __forceinline__ float gelu_erf(float x) {
  return 0.5f * x * (1.0f + erff(x * 0.70710678118654752f));
}
// tanh-approx GELU; max |err| ~3e-4 (experts only; gate keeps erf)
__device__ __forceinline__ float gelu_fast(float x) {
  float u = x * (0.79788456f + 0.035677408f * x * x);
  float ex;
  asm("v_exp_f32 %0, %1" : "=v"(ex) : "v"(-2.8853901f * u));
  float den = 1.0f + ex;
  float r;
  asm("v_rcp_f32 %0, %1" : "=v"(r) : "v"(den));
  return x * r;
}
__device__ __forceinline__ void gload16(const u16* g, char* lds) {
  __builtin_amdgcn_global_load_lds(
      (const __attribute__((address_space(1))) void*)g,
      (__attribute__((address_space(3))) void*)lds, 16, 0, 0);
}

// ---------------------------------------------------------------------------
// prep kernels (unchanged)
// ---------------------------------------------------------------------------
__global__ __launch_bounds__(256) void prep_x(const float* __restrict__ x,
                                              u16* __restrict__ xbf,
                                              u16* __restrict__ xlo) {
  size_t i = (size_t)blockIdx.x * 256 + threadIdx.x;
  float4 v = ((const float4*)x)[i];
  float a[4] = {v.x, v.y, v.z, v.w};
  union { u16 us[4]; unsigned long long ll; } hb, lb;
#pragma unroll
  for (int j = 0; j < 4; ++j) {
    u16 hu = f2bf(a[j]);
    hb.us[j] = hu;
    lb.us[j] = f2bf(a[j] - bfbits2f(hu));
  }
  *(unsigned long long*)(xbf + i * 4) = hb.ll;
  *(unsigned long long*)(xlo + i * 4) = lb.ll;
}

template <int C>
__global__ __launch_bounds__(256) void pack_w(const float* __restrict__ src,
                                              u16* __restrict__ dst, int R) {
  __shared__ float tl[64][65];
  const int e = blockIdx.z;
  const int k0 = blockIdx.x * 64, n0 = blockIdx.y * 64;
  const float* s = src + (size_t)e * R * C;
  const int tr = threadIdx.x >> 2;
  const int tc4 = (threadIdx.x & 3) * 16;
#pragma unroll
  for (int j = 0; j < 4; ++j) {
    float4 v = *(const float4*)(s + (size_t)(k0 + tr) * C + n0 + tc4 + j * 4);
    tl[tr][tc4 + j * 4 + 0] = v.x;
    tl[tr][tc4 + j * 4 + 1] = v.y;
    tl[tr][tc4 + j * 4 + 2] = v.z;
    tl[tr][tc4 + j * 4 + 3] = v.w;
  }
  __syncthreads();
  const int nl = threadIdx.x >> 2;
  const int kl = (threadIdx.x & 3) * 16;
  const int n = n0 + nl;
  const int sx = (n >> 1) & 3;
  const int t = (k0 + kl) >> 5;
  const int q0 = ((k0 + kl) & 31) >> 3;
#pragma unroll
  for (int c = 0; c < 2; ++c) {
    int q = q0 + c;
    int p = q ^ sx;
    union { u16 us[8]; unsigned long long ll[2]; } o;
#pragma unroll
    for (int j = 0; j < 8; ++j) o.us[j] = f2bf(tl[kl + c * 8 + j][nl]);
    u16* d = dst + (((size_t)e * (R / 32) + t) * C + n) * 32 + p * 8;
    ((unsigned long long*)d)[0] = o.ll[0];
    ((unsigned long long*)d)[1] = o.ll[1];
  }
}

__global__ __launch_bounds__(256) void prep_wcat(const float* __restrict__ gw1,
                                                 u16* __restrict__ wp) {
  int idx = blockIdx.x * 256 + threadIdx.x;
  int p = idx & 3;
  int n = (idx >> 2) & 511;
  int t = idx >> 11;
  int q = p ^ ((n >> 1) & 3);
  int k0 = t * 32 + q * 8;
  union { u16 us[8]; unsigned long long ll[2]; } o;
#pragma unroll
  for (int j = 0; j < 8; ++j) {
    int k = k0 + j;
    u16 v;
    if (k < 512) {
      v = f2bf(gw1[k * 512 + n]);
    } else if (k < 1024) {
      float w = gw1[(k - 512) * 512 + n];
      v = f2bf(w - bfbits2f(f2bf(w)));
    } else {
      v = f2bf(gw1[(k - 1024) * 512 + n]);
    }
    o.us[j] = v;
  }
  unsigned long long* d = (unsigned long long*)(wp + (size_t)idx * 8);
  d[0] = o.ll[0];
  d[1] = o.ll[1];
}

__global__ __launch_bounds__(256) void prep_w2t(const float* __restrict__ gw2,
                                                float* __restrict__ w2t) {
  int i = blockIdx.x * 256 + threadIdx.x;
  int e = i >> 9, k = i & 511;
  w2t[i] = gw2[k * 8 + e];
}

// ---------------------------------------------------------------------------
// core GEMM (r13 structure). LNOUT=1: +bias, LN, GELU -> bf16 out.
// LNOUT=0: raw fp32 partials (gate K-split).
// ---------------------------------------------------------------------------
template <int FM, int ROUTED, int GATHER, int LNOUT, int FAST>
__global__ __launch_bounds__(512, 2) void gemm_core(
    const u16* __restrict__ A, const u16* __restrict__ A2,
    const u16* __restrict__ Wp, long w_estride, int klen, long osplit,
    const float* __restrict__ bias, int b_estride,
    const float* __restrict__ lng, const float* __restrict__ lnb,
    u16* __restrict__ outb, float* __restrict__ outf,
    const int* __restrict__ slot_token, const int* __restrict__ blk_e,
    const int* __restrict__ blk_tok0) {
  constexpr int BM = FM * 32;
  constexpr int AG = FM * 2;
  constexpr int ABYTES = BM * 64;
  constexpr int BUF = ABYTES + 32768;
  constexpr int NL = AG + 32;
  constexpr int L = (NL + 7) / 8;
  constexpr int TSU = 16384;
  extern __shared__ char smem[];

  const int tid = threadIdx.x;
  const int lane = tid & 63;
  const int wv = tid >> 6;
  const int wm = (wv & 1) * (FM * 16);
  const int wn = (wv >> 1) * 128;
  const int l15 = lane & 15;
  const int lk = lane >> 4;
  const int swzk16 = (lk ^ ((l15 >> 1) & 3)) << 4;

  int e, row0, kt0, kbase;
  if (ROUTED) {
    e = blk_e[blockIdx.x];
    if (e < 0) return;
    row0 = blk_tok0[blockIdx.x];
    kt0 = 0; kbase = 0;
  } else {
    e = 0;
    row0 = blockIdx.x * BM;
    kbase = blockIdx.y * klen;
    kt0 = kbase >> 5;
  }
  const u16* We = Wp + (size_t)e * w_estride;

  const int lrq = lane >> 2;
  const int cse = (((lane & 3) ^ ((lane >> 3) & 3)) << 3);
  size_t off[L];
  int ldsoff[L], typ[L];
#pragma unroll
  for (int i = 0; i < L; ++i) {
    int id = wv + 8 * i;
    if (id >= NL) { typ[i] = 2; off[i] = 0; ldsoff[i] = 0; continue; }
    if (id < AG) {
      int lr = id * 16 + lrq;
      long grow = GATHER ? (long)slot_token[row0 + lr] : (long)(row0 + lr);
      off[i] = (size_t)grow * 512 + cse;
      ldsoff[i] = id * 1024 + lane * 16;
      typ[i] = 0;
    } else {
      int bg = id - AG;
      off[i] = (size_t)bg * 512 + lane * 8;
      ldsoff[i] = ABYTES + bg * 1024 + lane * 16;
      typ[i] = 1;
    }
  }

  auto STAGE = [&](int t, char* b) {
    const int kg = kbase + t * 32;
    const u16* Aseg = A;
    int kc = kg;
    if (A2) {
      if (kg >= 1024) { Aseg = A2; kc = kg - 1024; }
      else if (kg >= 512) kc = kg - 512;
    }
    const u16* Bt = We + (size_t)(kt0 + t) * TSU;
#pragma unroll
    for (int i = 0; i < L; ++i) {
      if (typ[i] == 0)      gload16(Aseg + off[i] + kc, b + ldsoff[i]);
      else if (typ[i] == 1) gload16(Bt + off[i], b + ldsoff[i]);
    }
  };

  f32x4 acc[FM][8];
#pragma unroll
  for (int i = 0; i < FM; ++i)
#pragma unroll
    for (int j = 0; j < 8; ++j) acc[i][j] = (f32x4){0.f, 0.f, 0.f, 0.f};

  const int nt = klen / 32;
  char* buf0 = smem;
  char* buf1 = smem + BUF;

  STAGE(0, buf0);
  __syncthreads();
  for (int t = 0; t < nt; ++t) {
    char* cur = (t & 1) ? buf1 : buf0;
    char* nxt = (t & 1) ? buf0 : buf1;
    if (t + 1 < nt) STAGE(t + 1, nxt);
    char* cB = cur + ABYTES;
    bf16x8 af[FM];
#pragma unroll
    for (int fm = 0; fm < FM; ++fm)
      af[fm] = *(const bf16x8*)(cur + (wm + fm * 16 + l15) * 64 + swzk16);
#pragma unroll
    for (int fn = 0; fn < 8; ++fn) {
      bf16x8 bv = *(const bf16x8*)(cB + (wn + fn * 16 + l15) * 64 + swzk16);
#pragma unroll
      for (int fm = 0; fm < FM; ++fm)
        acc[fm][fn] = __builtin_amdgcn_mfma_f32_16x16x32_bf16(
            af[fm], bv, acc[fm][fn], 0, 0, 0);
    }
    __syncthreads();
  }

  if constexpr (LNOUT) {
    const float* be = bias + (size_t)e * b_estride;
    const float* ge = lng + (size_t)e * b_estride;
    const float* bbe = lnb + (size_t)e * b_estride;
    float bias_v[8], g_v[8], b_v[8];
#pragma unroll
    for (int fn = 0; fn < 8; ++fn) {
      int col = wn + fn * 16 + l15;
      bias_v[fn] = be[col]; g_v[fn] = ge[col]; b_v[fn] = bbe[col];
    }
#pragma unroll
    for (int fm = 0; fm < FM; ++fm)
#pragma unroll
      for (int fn = 0; fn < 8; ++fn)
#pragma unroll
        for (int r = 0; r < 4; ++r) acc[fm][fn][r] += bias_v[fn];

    float* redS1 = (float*)smem;
    float* redS2 = redS1 + 4 * BM;
    const int g = wv >> 1;
#pragma unroll
    for (int fm = 0; fm < FM; ++fm)
#pragma unroll
      for (int r = 0; r < 4; ++r) {
        float a1 = 0.f, a2 = 0.f;
#pragma unroll
        for (int fn = 0; fn < 8; ++fn) {
          float v = acc[fm][fn][r];
          a1 += v; a2 += v * v;
        }
#pragma unroll
        for (int m = 1; m < 16; m <<= 1) {
          a1 += __shfl_xor(a1, m, 64);
          a2 += __shfl_xor(a2, m, 64);
        }
        if (l15 == 0) {
          int row = wm + fm * 16 + lk * 4 + r;
          redS1[g * BM + row] = a1;
          redS2[g * BM + row] = a2;
        }
      }
    __syncthreads();
#pragma unroll
    for (int fm = 0; fm < FM; ++fm)
#pragma unroll
      for (int r = 0; r < 4; ++r) {
        int row = wm + fm * 16 + lk * 4 + r;
        float S1 = 0.f, S2 = 0.f;
#pragma unroll
        for (int q = 0; q < 4; ++q) {
          S1 += redS1[q * BM + row];
          S2 += redS2[q * BM + row];
        }
        float mu = S1 * (1.0f / 512.0f);
        float var = S2 * (1.0f / 512.0f) - mu * mu;
        float rs = rsqrtf(var + 1e-5f);
        size_t rowg = (size_t)(row0 + row);
#pragma unroll
        for (int fn = 0; fn < 8; ++fn) {
          int col = wn + fn * 16 + l15;
          float v = (acc[fm][fn][r] - mu) * rs * g_v[fn] + b_v[fn];
          v = FAST ? gelu_fast(v) : gelu_erf(v);
          outb[rowg * 512 + col] = f2bf(v);
        }
      }
  } else {
    float* dst = outf + (size_t)blockIdx.y * osplit;
#pragma unroll
    for (int fm = 0; fm < FM; ++fm)
#pragma unroll
      for (int r = 0; r < 4; ++r) {
        size_t rowg = (size_t)(row0 + wm + fm * 16 + lk * 4 + r);
#pragma unroll
        for (int fn = 0; fn < 8; ++fn)
          dst[rowg * 512 + wn + fn * 16 + l15] = acc[fm][fn][r];
      }
  }
}

// ---------------------------------------------------------------------------
// Fused L2 + GEMM3: phase 1 = h1 @ W2 + LN + GELU (h2 stays in registers),
// phase 2 = h2 @ W3 via 8 col-chunks through swizzled LDS, eo written.
// ---------------------------------------------------------------------------
__global__ __launch_bounds__(512, 2) void gemm_l2eo(
    const u16* __restrict__ A, const u16* __restrict__ Wp,
    const u16* __restrict__ W3p, const float* __restrict__ bias,
    const float* __restrict__ lng, const float* __restrict__ lnb,
    const float* __restrict__ b3, const float* __restrict__ slot_w,
    const int* __restrict__ blk_e, const int* __restrict__ blk_tok0,
    float* __restrict__ eo) {
  constexpr int FM = 5, BM = 160, AG = 10;
  constexpr int ABYTES = BM * 64;
  constexpr int BUF = ABYTES + 32768;
  constexpr int NL = AG + 32;
  constexpr int L = 6;
  constexpr int TSU = 16384;
  extern __shared__ char smem[];

  const int tid = threadIdx.x;
  const int lane = tid & 63;
  const int wv = tid >> 6;
  const int wm = (wv & 1) * 80;
  const int wn = (wv >> 1) * 128;
  const int l15 = lane & 15;
  const int lk = lane >> 4;
  const int swzk16 = (lk ^ ((l15 >> 1) & 3)) << 4;

  int e = blk_e[blockIdx.x];
  if (e < 0) return;
  const int row0 = blk_tok0[blockIdx.x];
  const u16* We = Wp + (size_t)e * (512 * 512);

  const int lrq = lane >> 2;
  const int cse = (((lane & 3) ^ ((lane >> 3) & 3)) << 3);
  size_t off[L];
  int ldsoff[L], typ[L];
#pragma unroll
  for (int i = 0; i < L; ++i) {
    int id = wv + 8 * i;
    if (id >= NL) { typ[i] = 2; off[i] = 0; ldsoff[i] = 0; continue; }
    if (id < AG) {
      off[i] = (size_t)(row0 + id * 16 + lrq) * 512 + cse;
      ldsoff[i] = id * 1024 + lane * 16;
      typ[i] = 0;
    } else {
      int bg = id - AG;
      off[i] = (size_t)bg * 512 + lane * 8;
      ldsoff[i] = ABYTES + bg * 1024 + lane * 16;
      typ[i] = 1;
    }
  }

  auto STAGE = [&](int t, char* b) {
    const u16* Bt = We + (size_t)t * TSU;
#pragma unroll
    for (int i = 0; i < L; ++i) {
      if (typ[i] == 0)      gload16(A + off[i] + t * 32, b + ldsoff[i]);
      else if (typ[i] == 1) gload16(Bt + off[i], b + ldsoff[i]);
    }
  };

  f32x4 acc[FM][8];
#pragma unroll
  for (int i = 0; i < FM; ++i)
#pragma unroll
    for (int j = 0; j < 8; ++j) acc[i][j] = (f32x4){0.f, 0.f, 0.f, 0.f};

  char* buf0 = smem;
  char* buf1 = smem + BUF;

  STAGE(0, buf0);
  __syncthreads();
  for (int t = 0; t < 16; ++t) {
    char* cur = (t & 1) ? buf1 : buf0;
    char* nxt = (t & 1) ? buf0 : buf1;
    if (t + 1 < 16) STAGE(t + 1, nxt);
    char* cB = cur + ABYTES;
    bf16x8 af[FM];
#pragma unroll
    for (int fm = 0; fm < FM; ++fm)
      af[fm] = *(const bf16x8*)(cur + (wm + fm * 16 + l15) * 64 + swzk16);
#pragma unroll
    for (int fn = 0; fn < 8; ++fn) {
      bf16x8 bv = *(const bf16x8*)(cB + (wn + fn * 16 + l15) * 64 + swzk16);
#pragma unroll
      for (int fm = 0; fm < FM; ++fm)
        acc[fm][fn] = __builtin_amdgcn_mfma_f32_16x16x32_bf16(
            af[fm], bv, acc[fm][fn], 0, 0, 0);
    }
    __syncthreads();
  }

  // ---- LN + GELU; h2 kept in acc ----
  {
    const float* be = bias + (size_t)e * 512;
    const float* ge = lng + (size_t)e * 512;
    const float* bbe = lnb + (size_t)e * 512;
    float bias_v[8], g_v[8], b_v[8];
#pragma unroll
    for (int fn = 0; fn < 8; ++fn) {
      int col = wn + fn * 16 + l15;
      bias_v[fn] = be[col]; g_v[fn] = ge[col]; b_v[fn] = bbe[col];
    }
#pragma unroll
    for (int fm = 0; fm < FM; ++fm)
#pragma unroll
      for (int fn = 0; fn < 8; ++fn)
#pragma unroll
        for (int r = 0; r < 4; ++r) acc[fm][fn][r] += bias_v[fn];

    float* redS1 = (float*)smem;
    float* redS2 = redS1 + 4 * BM;
    const int g = wv >> 1;
#pragma unroll
    for (int fm = 0; fm < FM; ++fm)
#pragma unroll
      for (int r = 0; r < 4; ++r) {
        float a1 = 0.f, a2 = 0.f;
#pragma unroll
        for (int fn = 0; fn < 8; ++fn) {
          float v = acc[fm][fn][r];
          a1 += v; a2 += v * v;
        }
#pragma unroll
        for (int m = 1; m < 16; m <<= 1) {
          a1 += __shfl_xor(a1, m, 64);
          a2 += __shfl_xor(a2, m, 64);
        }
        if (l15 == 0) {
          int row = wm + fm * 16 + lk * 4 + r;
          redS1[g * BM + row] = a1;
          redS2[g * BM + row] = a2;
        }
      }
    __syncthreads();
#pragma unroll
    for (int fm = 0; fm < FM; ++fm)
#pragma unroll
      for (int r = 0; r < 4; ++r) {
        int row = wm + fm * 16 + lk * 4 + r;
        float S1 = 0.f, S2 = 0.f;
#pragma unroll
        for (int q = 0; q < 4; ++q) {
          S1 += redS1[q * BM + row];
          S2 += redS2[q * BM + row];
        }
        float mu = S1 * (1.0f / 512.0f);
        float var = S2 * (1.0f / 512.0f) - mu * mu;
        float rs = rsqrtf(var + 1e-5f);
#pragma unroll
        for (int fn = 0; fn < 8; ++fn) {
          float v = (acc[fm][fn][r] - mu) * rs * g_v[fn] + b_v[fn];
          acc[fm][fn][r] = gelu_fast(v);
        }
      }
  }

  // ---- phase 2: eo = h2 @ W3, 8 col-chunks of 64 through LDS ----
  const u16* W3e = W3p + (size_t)e * 32768;   // 16 tiles x 2048 u16
  char* A2 = smem;                            // [160][128B], XOR p=q^(row&7)
  char* B3 = smem + 20480;                    // 8 KB (2 W3 tiles)
  const int g2 = wv >> 1;
  const int wn3 = g2 * 16;
  float b3v = b3[e * 64 + wn3 + l15];
  float swr[5][4];
#pragma unroll
  for (int fm = 0; fm < 5; ++fm)
#pragma unroll
    for (int r = 0; r < 4; ++r)
      swr[fm][r] = slot_w[row0 + wm + fm * 16 + lk * 4 + r];

  f32x4 eacc[5];
#pragma unroll
  for (int j = 0; j < 5; ++j) eacc[j] = (f32x4){0.f, 0.f, 0.f, 0.f};

#pragma unroll
  for (int cc = 0; cc < 8; ++cc) {
    __syncthreads();   // prior chunk reads done / LN redS reads done (cc=0)
    if ((cc >> 1) == g2) {
      constexpr int FNB = 0;  // placeholder; real fnb below is compile-time
#pragma unroll
      for (int fd = 0; fd < 4; ++fd) {
        const int fn = (cc & 1) * 4 + fd;     // compile-time (cc unrolled)
#pragma unroll
        for (int fm = 0; fm < 5; ++fm)
#pragma unroll
          for (int r = 0; r < 4; ++r) {
            int row = wm + fm * 16 + lk * 4 + r;
            int colb = (fd * 16 + l15) * 2;
            int p = (colb >> 4) ^ (row & 7);
            *(u16*)(A2 + row * 128 + p * 16 + (colb & 15)) =
                f2bf(acc[fm][fn][r]);
          }
      }
      (void)FNB;
    }
    gload16(W3e + (size_t)(2 * cc) * 2048 + (size_t)tid * 8,
            B3 + (size_t)tid * 16);
    __syncthreads();
#pragma unroll
    for (int ss = 0; ss < 2; ++ss) {
      bf16x8 bv = *(const bf16x8*)(B3 + ss * 4096 + (wn3 + l15) * 64 + swzk16);
#pragma unroll
      for (int fm = 0; fm < 5; ++fm) {
        int row = wm + fm * 16 + l15;
        int p = (ss * 4 + lk) ^ (row & 7);
        bf16x8 av = *(const bf16x8*)(A2 + row * 128 + p * 16);
        eacc[fm] = __builtin_amdgcn_mfma_f32_16x16x32_bf16(av, bv, eacc[fm],
                                                           0, 0, 0);
      }
    }
  }

#pragma unroll
  for (int fm = 0; fm < 5; ++fm)
#pragma unroll
    for (int r = 0; r < 4; ++r) {
      int row = wm + fm * 16 + lk * 4 + r;
      eo[(size_t)(row0 + row) * 64 + wn3 + l15] =
          swr[fm][r] * (eacc[fm][r] + b3v);
    }
}

// ---------------------------------------------------------------------------
// gate tail (unchanged)
// ---------------------------------------------------------------------------
__global__ __launch_bounds__(256) void gate2_topk(
    const float* __restrict__ gh0, const float* __restrict__ gh1,
    const float* __restrict__ b1, const float* __restrict__ lng,
    const float* __restrict__ lnb, const float* __restrict__ w2t,
    const float* __restrict__ b2, float* __restrict__ gwout,
    float* __restrict__ idxout, float* __restrict__ tkwout) {
  const int lane = threadIdx.x & 63;
  const int wv = threadIdx.x >> 6;
  const int t = blockIdx.x * 4 + wv;
  const int c0 = lane * 8;
  float v[8];
  {
    float4 a0 = *(const float4*)(gh0 + (size_t)t * 512 + c0);
    float4 a1 = *(const float4*)(gh0 + (size_t)t * 512 + c0 + 4);
    float4 h0 = *(const float4*)(gh1 + (size_t)t * 512 + c0);
    float4 h1 = *(const float4*)(gh1 + (size_t)t * 512 + c0 + 4);
    float4 bb0 = *(const float4*)(b1 + c0);
    float4 bb1 = *(const float4*)(b1 + c0 + 4);
    v[0] = a0.x + h0.x + bb0.x; v[1] = a0.y + h0.y + bb0.y;
    v[2] = a0.z + h0.z + bb0.z; v[3] = a0.w + h0.w + bb0.w;
    v[4] = a1.x + h1.x + bb1.x; v[5] = a1.y + h1.y + bb1.y;
    v[6] = a1.z + h1.z + bb1.z; v[7] = a1.w + h1.w + bb1.w;
  }
  float s1 = 0.f, s2 = 0.f;
#pragma unroll
  for (int j = 0; j < 8; ++j) { s1 += v[j]; s2 += v[j] * v[j]; }
#pragma unroll
  for (int m = 1; m < 64; m <<= 1) {
    s1 += __shfl_xor(s1, m, 64);
    s2 += __shfl_xor(s2, m, 64);
  }
  float mu = s1 * (1.0f / 512.0f);
  float var = s2 * (1.0f / 512.0f) - mu * mu;
  float rs = rsqrtf(var + 1e-5f);
  float y[8];
  {
    float4 g0 = *(const float4*)(lng + c0);
    float4 g1 = *(const float4*)(lng + c0 + 4);
    float4 q0 = *(const float4*)(lnb + c0);
    float4 q1 = *(const float4*)(lnb + c0 + 4);
    float gg[8] = {g0.x, g0.y, g0.z, g0.w, g1.x, g1.y, g1.z, g1.w};
    float qq[8] = {q0.x, q0.y, q0.z, q0.w, q1.x, q1.y, q1.z, q1.w};
#pragma unroll
    for (int j = 0; j < 8; ++j)
      y[j] = gelu_erf((v[j] - mu) * rs * gg[j] + qq[j]);
  }
  float logit[8];
#pragma unroll
  for (int e = 0; e < 8; ++e) {
    const float4* wr = (const float4*)(w2t + e * 512 + c0);
    float4 w0 = wr[0], w1 = wr[1];
    float p = y[0] * w0.x + y[1] * w0.y + y[2] * w0.z + y[3] * w0.w +
              y[4] * w1.x + y[5] * w1.y + y[6] * w1.z + y[7] * w1.w;
#pragma unroll
    for (int m = 1; m < 64; m <<= 1) p += __shfl_xor(p, m, 64);
    logit[e] = p + b2[e];
  }
  if (lane == 0) {
    float mx = logit[0];
#pragma unroll
    for (int e = 1; e < 8; ++e) mx = fmaxf(mx, logit[e]);
    float w[8], ssum = 0.f;
#pragma unroll
    for (int e = 0; e < 8; ++e) { w[e] = expf(logit[e] - mx); ssum += w[e]; }
    float inv = 1.0f / ssum;
#pragma unroll
    for (int e = 0; e < 8; ++e) w[e] *= inv;
    float w1v = -1.f, w2v = -1.f; int i1 = 0, i2 = 0;
#pragma unroll
    for (int e = 0; e < 8; ++e) {
      float vv = w[e];
      if (vv > w1v)      { w2v = w1v; i2 = i1; w1v = vv; i1 = e; }
      else if (vv > w2v) { w2v = vv; i2 = e; }
    }
    float s = w1v + w2v;
#pragma unroll
    for (int e = 0; e < 8; ++e) gwout[t * 8 + e] = w[e];
    idxout[t * 2] = (float)i1; idxout[t * 2 + 1] = (float)i2;
    tkwout[t * 2] = w1v / s;   tkwout[t * 2 + 1] = w2v / s;
  }
}

__global__ __launch_bounds__(256) void usage_k(const float* __restrict__ gw,
                                               float* __restrict__ usage) {
  __shared__ float r[256];
  int e = blockIdx.x;
  float s = 0.f;
  for (int t = threadIdx.x; t < N_TOK; t += 256) s += gw[t * 8 + e];
  r[threadIdx.x] = s;
  __syncthreads();
  for (int st = 128; st > 0; st >>= 1) {
    if (threadIdx.x < st) r[threadIdx.x] += r[threadIdx.x + st];
    __syncthreads();
  }
  if (threadIdx.x == 0) usage[e] = r[0] * (1.0f / (float)N_TOK);
}

// ---------------------------------------------------------------------------
// routing (160-row tiles, XCD-clustered block table — r13)
// ---------------------------------------------------------------------------
__global__ __launch_bounds__(256) void count_hist(const float* __restrict__ idxout,
                                                  int* __restrict__ blk_cnt) {
  __shared__ int h[8];
  if (threadIdx.x < 8) h[threadIdx.x] = 0;
  __syncthreads();
  int t = blockIdx.x * 256 + threadIdx.x;
  int e0 = (int)idxout[t * 2], e1 = (int)idxout[t * 2 + 1];
  atomicAdd(&h[e0], 1);
  atomicAdd(&h[e1], 1);
  __syncthreads();
  if (threadIdx.x < 8) blk_cnt[blockIdx.x * 8 + threadIdx.x] = h[threadIdx.x];
}

__global__ __launch_bounds__(512) void k_offsets2(
    const int* __restrict__ blk_cnt, int* __restrict__ sbase,
    int* __restrict__ blk_e, int* __restrict__ blk_tok0) {
  __shared__ int cnt[64][8];
  __shared__ int ecnt[8];
  __shared__ int offs[8];
  __shared__ int nbtot;
  const int tid = threadIdx.x;
  cnt[tid >> 3][tid & 7] = blk_cnt[tid];
  __syncthreads();
  if (tid < 8) {
    int s = 0;
    for (int b = 0; b < 64; ++b) s += cnt[b][tid];
    ecnt[tid] = s;
  }
  __syncthreads();
  if (tid == 0) {
    int off = 0, nb = 0;
    for (int e = 0; e < 8; ++e) {
      offs[e] = off;
      int nbe = (ecnt[e] + 159) / 160;
      off += nbe * 160;
      nb += nbe;
    }
    nbtot = nb;
  }
  __syncthreads();
  {
    int b = tid >> 3, e = tid & 7;
    int s = offs[e];
    for (int bp = 0; bp < b; ++bp) s += cnt[bp][e];
    sbase[tid] = s;
  }
  const int q = (nbtot + 7) >> 3;
  for (int b = tid; b < MAX_BLOCKS; b += 512) {
    int xcd = b & 7, i = b >> 3;
    int j = xcd * q + i;
    int be = -1, bt = 0;
    if (i < q && j < nbtot) {
      int acc = 0;
#pragma unroll
      for (int e = 0; e < 8; ++e) {
        int nbe = (ecnt[e] + 159) / 160;
        if (j >= acc && j < acc + nbe) { be = e; bt = offs[e] + (j - acc) * 160; }
        acc += nbe;
      }
    }
    blk_e[b] = be;
    blk_tok0[b] = bt;
  }
}

__global__ __launch_bounds__(256) void k_padinit(int* __restrict__ slot_token,
                                                 float* __restrict__ slot_w) {
  int i = blockIdx.x * 256 + threadIdx.x;
  if (i < MAX_SLOTS) { slot_token[i] = 0; slot_w[i] = 0.f; }
}

__global__ __launch_bounds__(256) void k_scatter2(
    const float* __restrict__ idxout, const float* __restrict__ tkwout,
    const int* __restrict__ sbase, int* __restrict__ slot_token,
    float* __restrict__ slot_w, int* __restrict__ tok_slot) {
  __shared__ int lpos[8];
  if (threadIdx.x < 8) lpos[threadIdx.x] = 0;
  __syncthreads();
  int t = blockIdx.x * 256 + threadIdx.x;
#pragma unroll
  for (int k = 0; k < 2; ++k) {
    int e = (int)idxout[t * 2 + k];
    int lr = atomicAdd(&lpos[e], 1);
    int s = sbase[blockIdx.x * 8 + e] + lr;
    slot_token[s] = t;
    slot_w[s] = tkwout[t * 2 + k];
    tok_slot[t * 2 + k] = s;
  }
}

// ---------------------------------------------------------------------------
// combine + final 64x64 projection (unchanged)
// ---------------------------------------------------------------------------
__global__ __launch_bounds__(256) void combine_proj(
    const float* __restrict__ eo, const int* __restrict__ tok_slot,
    const float* __restrict__ pw, const float* __restrict__ pb,
    float* __restrict__ outp) {
  __shared__ float cs[64][68];
  __shared__ float pws[64][68];
  const int t0 = blockIdx.x * 64;
  const int tq = threadIdx.x & 3;
  const int tt = threadIdx.x >> 2;
#pragma unroll
  for (int j = 0; j < 4; ++j) {
    float4 v = *(const float4*)(pw + tt * 64 + tq * 16 + j * 4);
    *(float4*)&pws[tt][tq * 16 + j * 4] = v;
  }
  {
    int t = t0 + tt;
    int s1 = tok_slot[t * 2], s2 = tok_slot[t * 2 + 1];
#pragma unroll
    for (int j = 0; j < 4; ++j) {
      float4 a = *(const float4*)(eo + (size_t)s1 * 64 + tq * 16 + j * 4);
      float4 b = *(const float4*)(eo + (size_t)s2 * 64 + tq * 16 + j * 4);
      float4 c = {a.x + b.x, a.y + b.y, a.z + b.z, a.w + b.w};
      *(float4*)&cs[tt][tq * 16 + j * 4] = c;
    }
  }
  __syncthreads();
  float o[16];
#pragma unroll
  for (int i = 0; i < 16; ++i) o[i] = 0.f;
  for (int j = 0; j < 64; ++j) {
    float c = cs[tt][j];
#pragma unroll
    for (int q4 = 0; q4 < 4; ++q4) {
      float4 p = *(const float4*)&pws[j][tq * 16 + q4 * 4];
      o[q4 * 4 + 0] += c * p.x;
      o[q4 * 4 + 1] += c * p.y;
      o[q4 * 4 + 2] += c * p.z;
      o[q4 * 4 + 3] += c * p.w;
    }
  }
#pragma unroll
  for (int i = 0; i < 16; ++i)
    outp[(size_t)(t0 + tt) * 64 + tq * 16 + i] = o[i] + pb[tq * 16 + i];
}

// ---------------------------------------------------------------------------
extern "C" void kernel_launch(void* const* d_in, const int* in_sizes, int n_in,
                              void* d_out, int out_size, void* d_ws, size_t ws_size,
                              hipStream_t stream) {
  const float* x      = (const float*)d_in[0];
  const float* g_w1   = (const float*)d_in[1];
  const float* g_b1   = (const float*)d_in[2];
  const float* g_lng  = (const float*)d_in[3];
  const float* g_lnb  = (const float*)d_in[4];
  const float* g_w2   = (const float*)d_in[5];
  const float* g_b2   = (const float*)d_in[6];
  const float* e_w1   = (const float*)d_in[7];
  const float* e_b1   = (const float*)d_in[8];
  const float* e_ln1g = (const float*)d_in[9];
  const float* e_ln1b = (const float*)d_in[10];
  const float* e_w2   = (const float*)d_in[11];
  const float* e_b2   = (const float*)d_in[12];
  const float* e_ln2g = (const float*)d_in[13];
  const float* e_ln2b = (const float*)d_in[14];
  const float* e_w3   = (const float*)d_in[15];
  const float* e_b3   = (const float*)d_in[16];
  const float* p_w    = (const float*)d_in[17];
  const float* p_b    = (const float*)d_in[18];

  char* ws = (char*)d_ws;
  u16*   x_bf  = (u16*)(ws);                      // 16 MB
  u16*   x_lo  = (u16*)(ws + (16ull << 20));      // 16 MB
  u16*   e_w1p = (u16*)(ws + (32ull << 20));      // 4 MB
  u16*   e_w2p = (u16*)(ws + (36ull << 20));      // 4 MB
  u16*   e_w3p = (u16*)(ws + (40ull << 20));      // 0.5 MB
  u16*   wcat  = (u16*)(ws + (41ull << 20));      // 1.5 MB
  float* w2t   = (float*)(ws + (43ull << 20));    // 16 KB
  float* gh0   = (float*)(ws + (44ull << 20));    // 44..76 (contiguous w/ gh1)
  float* gh1   = (float*)(ws + (76ull << 20));    // 76..108
  u16*   h     = (u16*)(ws + (44ull << 20));      // overlays after gate
  float* eo    = (float*)(ws + (112ull << 20));   // 112..120.8
  int*   slot_token = (int*)(ws + (121ull << 20));
  float* slot_w     = (float*)(ws + (121ull << 20) + (1ull << 18));
  int*   tok_slot   = (int*)(ws + (121ull << 20) + (2ull << 18));
  int*   blk_cnt    = (int*)(ws + (122ull << 20));
  int*   sbase      = blk_cnt + 512;
  int*   blk_e      = blk_cnt + 1024;
  int*   blk_tok0   = blk_cnt + 2048;
  if (ws_size < (123ull << 20)) return;

  float* fout = (float*)d_out;
  float* o_output = fout;
  float* o_gatew  = fout + 1048576;
  float* o_idx    = fout + 1179648;
  float* o_topw   = fout + 1212416;
  float* o_usage  = fout + 1245184;

  (void)hipFuncSetAttribute((const void*)gemm_core<4, 0, 0, 0, 0>,
                            hipFuncAttributeMaxDynamicSharedMemorySize, 81920);
  (void)hipFuncSetAttribute((const void*)gemm_core<5, 1, 1, 1, 1>,
                            hipFuncAttributeMaxDynamicSharedMemorySize, 86016);
  (void)hipFuncSetAttribute((const void*)gemm_l2eo,
                            hipFuncAttributeMaxDynamicSharedMemorySize, 86016);

  // ---- prep ----
  prep_x<<<8192, 256, 0, stream>>>(x, x_bf, x_lo);
  pack_w<512><<<dim3(8, 8, 8), 256, 0, stream>>>(e_w1, e_w1p, 512);
  pack_w<512><<<dim3(8, 8, 8), 256, 0, stream>>>(e_w2, e_w2p, 512);
  pack_w<64><<<dim3(8, 1, 8), 256, 0, stream>>>(e_w3, e_w3p, 512);
  prep_wcat<<<384, 256, 0, stream>>>(g_w1, wcat);
  prep_w2t<<<16, 256, 0, stream>>>(g_w2, w2t);

  // ---- gate: BM=128 x ksplit2 -> 256 blocks ----
  gemm_core<4, 0, 0, 0, 0><<<dim3(N_TOK / 128, 2), 512, 81920, stream>>>(
      x_bf, x_lo, wcat, 0, 768, (long)N_TOK * 512, nullptr, 0,
      nullptr, nullptr, nullptr, gh0, nullptr, nullptr, nullptr);
  gate2_topk<<<N_TOK / 4, 256, 0, stream>>>(gh0, gh1, g_b1, g_lng, g_lnb,
                                            w2t, g_b2, o_gatew, o_idx, o_topw);
  usage_k<<<8, 256, 0, stream>>>(o_gatew, o_usage);

  // ---- routing ----
  count_hist<<<64, 256, 0, stream>>>(o_idx, blk_cnt);
  k_offsets2<<<1, 512, 0, stream>>>(blk_cnt, sbase, blk_e, blk_tok0);
  k_padinit<<<(MAX_SLOTS + 255) / 256, 256, 0, stream>>>(slot_token, slot_w);
  k_scatter2<<<64, 256, 0, stream>>>(o_idx, o_topw, sbase, slot_token, slot_w,
                                     tok_slot);

  // ---- experts: L1 (x -> h1), then fused L2+GEMM3 (h1 -> eo) ----
  gemm_core<5, 1, 1, 1, 1><<<MAX_BLOCKS, 512, 86016, stream>>>(
      x_bf, nullptr, e_w1p, 512 * 512, 512, 0, e_b1, 512,
      e_ln1g, e_ln1b, h, nullptr, slot_token, blk_e, blk_tok0);
  gemm_l2eo<<<MAX_BLOCKS, 512, 86016, stream>>>(
      h, e_w2p, e_w3p, e_b2, e_ln2g, e_ln2b, e_b3, slot_w,
      blk_e, blk_tok0, eo);
  combine_proj<<<N_TOK / 64, 256, 0, stream>>>(eo, tok_slot, p_w, p_b, o_output);
}

// Round 15
// 199.732 us; speedup vs baseline: 1.1840x; 1.1840x over previous
//
#include <hip/hip_runtime.h>
#include <hip/hip_bf16.h>

// Round 15: r13 (best measured, 206.8us) with launch-count reduction only:
// pack_w x3 merged, prep_wcat+prep_w2t merged, k_padinit folded into
// count_hist. 17 -> 13 dispatches. GEMM kernels byte-identical to r13.
#define N_TOK 16384
#define MAX_SLOTS 34080
#define MAX_BLOCKS 216

typedef __attribute__((ext_vector_type(8))) short bf16x8;
typedef __attribute__((ext_vector_type(4))) float f32x4;
typedef unsigned short u16;

__device__ __forceinline__ u16 f2bf(float f) {
  __hip_bfloat16 h = __float2bfloat16(f);
  union { __hip_bfloat16 b; u16 u; } c; c.b = h; return c.u;
}
__device__ __forceinline__ float bfbits2f(u16 u) {
  return __uint_as_float(((unsigned)u) << 16);
}
__device__ __forceinline__ float gelu_erf(float x) {
  return 0.5f * x * (1.0f + erff(x * 0.70710678118654752f));
}
// tanh-approx GELU; max |err| ~3e-4 (experts only; gate keeps erf)
__device__ __forceinline__ float gelu_fast(float x) {
  float u = x * (0.79788456f + 0.035677408f * x * x);
  float ex;
  asm("v_exp_f32 %0, %1" : "=v"(ex) : "v"(-2.8853901f * u));
  float den = 1.0f + ex;
  float r;
  asm("v_rcp_f32 %0, %1" : "=v"(r) : "v"(den));
  return x * r;
}
__device__ __forceinline__ void gload16(const u16* g, char* lds) {
  __builtin_amdgcn_global_load_lds(
      (const __attribute__((address_space(1))) void*)g,
      (__attribute__((address_space(3))) void*)lds, 16, 0, 0);
}

// ---------------------------------------------------------------------------
// prep kernels
// ---------------------------------------------------------------------------
__global__ __launch_bounds__(256) void prep_x(const float* __restrict__ x,
                                              u16* __restrict__ xbf,
                                              u16* __restrict__ xlo) {
  size_t i = (size_t)blockIdx.x * 256 + threadIdx.x;
  float4 v = ((const float4*)x)[i];
  float a[4] = {v.x, v.y, v.z, v.w};
  union { u16 us[4]; unsigned long long ll; } hb, lb;
#pragma unroll
  for (int j = 0; j < 4; ++j) {
    u16 hu = f2bf(a[j]);
    hb.us[j] = hu;
    lb.us[j] = f2bf(a[j] - bfbits2f(hu));
  }
  *(unsigned long long*)(xbf + i * 4) = hb.ll;
  *(unsigned long long*)(xlo + i * 4) = lb.ll;
}

// all three expert-weight packs in one launch: blocks 0..511 w1, 512..1023 w2,
// 1024..1087 w3. Each block packs one 64x64 tile -> tile-major swizzled bf16.
__global__ __launch_bounds__(256) void pack_w_all(
    const float* __restrict__ w1, const float* __restrict__ w2,
    const float* __restrict__ w3, u16* __restrict__ d1, u16* __restrict__ d2,
    u16* __restrict__ d3) {
  __shared__ float tl[64][65];
  const int bid = blockIdx.x;
  const float* src; u16* dst; int C, e, kx, ny;
  if (bid < 512) {
    src = w1; dst = d1; C = 512;
    int i = bid; e = i >> 6; kx = (i >> 3) & 7; ny = i & 7;
  } else if (bid < 1024) {
    src = w2; dst = d2; C = 512;
    int i = bid - 512; e = i >> 6; kx = (i >> 3) & 7; ny = i & 7;
  } else {
    src = w3; dst = d3; C = 64;
    int i = bid - 1024; e = i >> 3; kx = i & 7; ny = 0;
  }
  const int R = 512;
  const int k0 = kx * 64, n0 = ny * 64;
  const float* s = src + (size_t)e * R * C;
  const int tr = threadIdx.x >> 2;
  const int tc4 = (threadIdx.x & 3) * 16;
#pragma unroll
  for (int j = 0; j < 4; ++j) {
    float4 v = *(const float4*)(s + (size_t)(k0 + tr) * C + n0 + tc4 + j * 4);
    tl[tr][tc4 + j * 4 + 0] = v.x;
    tl[tr][tc4 + j * 4 + 1] = v.y;
    tl[tr][tc4 + j * 4 + 2] = v.z;
    tl[tr][tc4 + j * 4 + 3] = v.w;
  }
  __syncthreads();
  const int nl = threadIdx.x >> 2;
  if (nl >= C - n0 && C == 64 && nl >= 64) return;  // (never true; C>=64)
  const int kl = (threadIdx.x & 3) * 16;
  const int n = n0 + nl;
  const int sx = (n >> 1) & 3;
  const int t = (k0 + kl) >> 5;
  const int q0 = ((k0 + kl) & 31) >> 3;
#pragma unroll
  for (int c = 0; c < 2; ++c) {
    int q = q0 + c;
    int p = q ^ sx;
    union { u16 us[8]; unsigned long long ll[2]; } o;
#pragma unroll
    for (int j = 0; j < 8; ++j) o.us[j] = f2bf(tl[kl + c * 8 + j][nl]);
    u16* d = dst + (((size_t)e * (R / 32) + t) * C + n) * 32 + p * 8;
    ((unsigned long long*)d)[0] = o.ll[0];
    ((unsigned long long*)d)[1] = o.ll[1];
  }
}

// gate weight prep merged: blocks 0..383 build wcat (split-bf16 K=1536,
// packed BK=32 tiles); blocks 384..399 build w2t.
__global__ __launch_bounds__(256) void prep_gate_w(
    const float* __restrict__ gw1, u16* __restrict__ wp,
    const float* __restrict__ gw2, float* __restrict__ w2t) {
  const int bid = blockIdx.x;
  if (bid < 384) {
    int idx = bid * 256 + threadIdx.x;
    int p = idx & 3;
    int n = (idx >> 2) & 511;
    int t = idx >> 11;
    int q = p ^ ((n >> 1) & 3);
    int k0 = t * 32 + q * 8;
    union { u16 us[8]; unsigned long long ll[2]; } o;
#pragma unroll
    for (int j = 0; j < 8; ++j) {
      int k = k0 + j;
      u16 v;
      if (k < 512) {
        v = f2bf(gw1[k * 512 + n]);
      } else if (k < 1024) {
        float w = gw1[(k - 512) * 512 + n];
        v = f2bf(w - bfbits2f(f2bf(w)));
      } else {
        v = f2bf(gw1[(k - 1024) * 512 + n]);
      }
      o.us[j] = v;
    }
    unsigned long long* d = (unsigned long long*)(wp + (size_t)idx * 8);
    d[0] = o.ll[0];
    d[1] = o.ll[1];
  } else {
    int i = (bid - 384) * 256 + threadIdx.x;   // < 4096
    int e = i >> 9, k = i & 511;
    w2t[i] = gw2[k * 8 + e];
  }
}

// ---------------------------------------------------------------------------
// core GEMM (r13, unchanged). LNOUT=1: +bias, LN, GELU -> bf16 out.
// LNOUT=0: raw fp32 partials (gate K-split).
// ---------------------------------------------------------------------------
template <int FM, int ROUTED, int GATHER, int LNOUT, int FAST>
__global__ __launch_bounds__(512, 2) void gemm_core(
    const u16* __restrict__ A, const u16* __restrict__ A2,
    const u16* __restrict__ Wp, long w_estride, int klen, long osplit,
    const float* __restrict__ bias, int b_estride,
    const float* __restrict__ lng, const float* __restrict__ lnb,
    u16* __restrict__ outb, float* __restrict__ outf,
    const int* __restrict__ slot_token, const int* __restrict__ blk_e,
    const int* __restrict__ blk_tok0) {
  constexpr int BM = FM * 32;
  constexpr int AG = FM * 2;
  constexpr int ABYTES = BM * 64;
  constexpr int BUF = ABYTES + 32768;
  constexpr int NL = AG + 32;
  constexpr int L = (NL + 7) / 8;
  constexpr int TSU = 16384;
  extern __shared__ char smem[];

  const int tid = threadIdx.x;
  const int lane = tid & 63;
  const int wv = tid >> 6;
  const int wm = (wv & 1) * (FM * 16);
  const int wn = (wv >> 1) * 128;
  const int l15 = lane & 15;
  const int lk = lane >> 4;
  const int swzk16 = (lk ^ ((l15 >> 1) & 3)) << 4;

  int e, row0, kt0, kbase;
  if (ROUTED) {
    e = blk_e[blockIdx.x];
    if (e < 0) return;
    row0 = blk_tok0[blockIdx.x];
    kt0 = 0; kbase = 0;
  } else {
    e = 0;
    row0 = blockIdx.x * BM;
    kbase = blockIdx.y * klen;
    kt0 = kbase >> 5;
  }
  const u16* We = Wp + (size_t)e * w_estride;

  const int lrq = lane >> 2;
  const int cse = (((lane & 3) ^ ((lane >> 3) & 3)) << 3);
  size_t off[L];
  int ldsoff[L], typ[L];
#pragma unroll
  for (int i = 0; i < L; ++i) {
    int id = wv + 8 * i;
    if (id >= NL) { typ[i] = 2; off[i] = 0; ldsoff[i] = 0; continue; }
    if (id < AG) {
      int lr = id * 16 + lrq;
      long grow = GATHER ? (long)slot_token[row0 + lr] : (long)(row0 + lr);
      off[i] = (size_t)grow * 512 + cse;
      ldsoff[i] = id * 1024 + lane * 16;
      typ[i] = 0;
    } else {
      int bg = id - AG;
      off[i] = (size_t)bg * 512 + lane * 8;
      ldsoff[i] = ABYTES + bg * 1024 + lane * 16;
      typ[i] = 1;
    }
  }

  auto STAGE = [&](int t, char* b) {
    const int kg = kbase + t * 32;
    const u16* Aseg = A;
    int kc = kg;
    if (A2) {
      if (kg >= 1024) { Aseg = A2; kc = kg - 1024; }
      else if (kg >= 512) kc = kg - 512;
    }
    const u16* Bt = We + (size_t)(kt0 + t) * TSU;
#pragma unroll
    for (int i = 0; i < L; ++i) {
      if (typ[i] == 0)      gload16(Aseg + off[i] + kc, b + ldsoff[i]);
      else if (typ[i] == 1) gload16(Bt + off[i], b + ldsoff[i]);
    }
  };

  f32x4 acc[FM][8];
#pragma unroll
  for (int i = 0; i < FM; ++i)
#pragma unroll
    for (int j = 0; j < 8; ++j) acc[i][j] = (f32x4){0.f, 0.f, 0.f, 0.f};

  const int nt = klen / 32;
  char* buf0 = smem;
  char* buf1 = smem + BUF;

  STAGE(0, buf0);
  __syncthreads();
  for (int t = 0; t < nt; ++t) {
    char* cur = (t & 1) ? buf1 : buf0;
    char* nxt = (t & 1) ? buf0 : buf1;
    if (t + 1 < nt) STAGE(t + 1, nxt);
    char* cB = cur + ABYTES;
    bf16x8 af[FM];
#pragma unroll
    for (int fm = 0; fm < FM; ++fm)
      af[fm] = *(const bf16x8*)(cur + (wm + fm * 16 + l15) * 64 + swzk16);
#pragma unroll
    for (int fn = 0; fn < 8; ++fn) {
      bf16x8 bv = *(const bf16x8*)(cB + (wn + fn * 16 + l15) * 64 + swzk16);
#pragma unroll
      for (int fm = 0; fm < FM; ++fm)
        acc[fm][fn] = __builtin_amdgcn_mfma_f32_16x16x32_bf16(
            af[fm], bv, acc[fm][fn], 0, 0, 0);
    }
    __syncthreads();
  }

  if constexpr (LNOUT) {
    const float* be = bias + (size_t)e * b_estride;
    const float* ge = lng + (size_t)e * b_estride;
    const float* bbe = lnb + (size_t)e * b_estride;
    float bias_v[8], g_v[8], b_v[8];
#pragma unroll
    for (int fn = 0; fn < 8; ++fn) {
      int col = wn + fn * 16 + l15;
      bias_v[fn] = be[col]; g_v[fn] = ge[col]; b_v[fn] = bbe[col];
    }
#pragma unroll
    for (int fm = 0; fm < FM; ++fm)
#pragma unroll
      for (int fn = 0; fn < 8; ++fn)
#pragma unroll
        for (int r = 0; r < 4; ++r) acc[fm][fn][r] += bias_v[fn];

    float* redS1 = (float*)smem;
    float* redS2 = redS1 + 4 * BM;
    const int g = wv >> 1;
#pragma unroll
    for (int fm = 0; fm < FM; ++fm)
#pragma unroll
      for (int r = 0; r < 4; ++r) {
        float a1 = 0.f, a2 = 0.f;
#pragma unroll
        for (int fn = 0; fn < 8; ++fn) {
          float v = acc[fm][fn][r];
          a1 += v; a2 += v * v;
        }
#pragma unroll
        for (int m = 1; m < 16; m <<= 1) {
          a1 += __shfl_xor(a1, m, 64);
          a2 += __shfl_xor(a2, m, 64);
        }
        if (l15 == 0) {
          int row = wm + fm * 16 + lk * 4 + r;
          redS1[g * BM + row] = a1;
          redS2[g * BM + row] = a2;
        }
      }
    __syncthreads();
#pragma unroll
    for (int fm = 0; fm < FM; ++fm)
#pragma unroll
      for (int r = 0; r < 4; ++r) {
        int row = wm + fm * 16 + lk * 4 + r;
        float S1 = 0.f, S2 = 0.f;
#pragma unroll
        for (int q = 0; q < 4; ++q) {
          S1 += redS1[q * BM + row];
          S2 += redS2[q * BM + row];
        }
        float mu = S1 * (1.0f / 512.0f);
        float var = S2 * (1.0f / 512.0f) - mu * mu;
        float rs = rsqrtf(var + 1e-5f);
        size_t rowg = (size_t)(row0 + row);
#pragma unroll
        for (int fn = 0; fn < 8; ++fn) {
          int col = wn + fn * 16 + l15;
          float v = (acc[fm][fn][r] - mu) * rs * g_v[fn] + b_v[fn];
          v = FAST ? gelu_fast(v) : gelu_erf(v);
          outb[rowg * 512 + col] = f2bf(v);
        }
      }
  } else {
    float* dst = outf + (size_t)blockIdx.y * osplit;
#pragma unroll
    for (int fm = 0; fm < FM; ++fm)
#pragma unroll
      for (int r = 0; r < 4; ++r) {
        size_t rowg = (size_t)(row0 + wm + fm * 16 + lk * 4 + r);
#pragma unroll
        for (int fn = 0; fn < 8; ++fn)
          dst[rowg * 512 + wn + fn * 16 + l15] = acc[fm][fn][r];
      }
  }
}

// ---------------------------------------------------------------------------
// gate tail (unchanged)
// ---------------------------------------------------------------------------
__global__ __launch_bounds__(256) void gate2_topk(
    const float* __restrict__ gh0, const float* __restrict__ gh1,
    const float* __restrict__ b1, const float* __restrict__ lng,
    const float* __restrict__ lnb, const float* __restrict__ w2t,
    const float* __restrict__ b2, float* __restrict__ gwout,
    float* __restrict__ idxout, float* __restrict__ tkwout) {
  const int lane = threadIdx.x & 63;
  const int wv = threadIdx.x >> 6;
  const int t = blockIdx.x * 4 + wv;
  const int c0 = lane * 8;
  float v[8];
  {
    float4 a0 = *(const float4*)(gh0 + (size_t)t * 512 + c0);
    float4 a1 = *(const float4*)(gh0 + (size_t)t * 512 + c0 + 4);
    float4 h0 = *(const float4*)(gh1 + (size_t)t * 512 + c0);
    float4 h1 = *(const float4*)(gh1 + (size_t)t * 512 + c0 + 4);
    float4 bb0 = *(const float4*)(b1 + c0);
    float4 bb1 = *(const float4*)(b1 + c0 + 4);
    v[0] = a0.x + h0.x + bb0.x; v[1] = a0.y + h0.y + bb0.y;
    v[2] = a0.z + h0.z + bb0.z; v[3] = a0.w + h0.w + bb0.w;
    v[4] = a1.x + h1.x + bb1.x; v[5] = a1.y + h1.y + bb1.y;
    v[6] = a1.z + h1.z + bb1.z; v[7] = a1.w + h1.w + bb1.w;
  }
  float s1 = 0.f, s2 = 0.f;
#pragma unroll
  for (int j = 0; j < 8; ++j) { s1 += v[j]; s2 += v[j] * v[j]; }
#pragma unroll
  for (int m = 1; m < 64; m <<= 1) {
    s1 += __shfl_xor(s1, m, 64);
    s2 += __shfl_xor(s2, m, 64);
  }
  float mu = s1 * (1.0f / 512.0f);
  float var = s2 * (1.0f / 512.0f) - mu * mu;
  float rs = rsqrtf(var + 1e-5f);
  float y[8];
  {
    float4 g0 = *(const float4*)(lng + c0);
    float4 g1 = *(const float4*)(lng + c0 + 4);
    float4 q0 = *(const float4*)(lnb + c0);
    float4 q1 = *(const float4*)(lnb + c0 + 4);
    float gg[8] = {g0.x, g0.y, g0.z, g0.w, g1.x, g1.y, g1.z, g1.w};
    float qq[8] = {q0.x, q0.y, q0.z, q0.w, q1.x, q1.y, q1.z, q1.w};
#pragma unroll
    for (int j = 0; j < 8; ++j)
      y[j] = gelu_erf((v[j] - mu) * rs * gg[j] + qq[j]);
  }
  float logit[8];
#pragma unroll
  for (int e = 0; e < 8; ++e) {
    const float4* wr = (const float4*)(w2t + e * 512 + c0);
    float4 w0 = wr[0], w1 = wr[1];
    float p = y[0] * w0.x + y[1] * w0.y + y[2] * w0.z + y[3] * w0.w +
              y[4] * w1.x + y[5] * w1.y + y[6] * w1.z + y[7] * w1.w;
#pragma unroll
    for (int m = 1; m < 64; m <<= 1) p += __shfl_xor(p, m, 64);
    logit[e] = p + b2[e];
  }
  if (lane == 0) {
    float mx = logit[0];
#pragma unroll
    for (int e = 1; e < 8; ++e) mx = fmaxf(mx, logit[e]);
    float w[8], ssum = 0.f;
#pragma unroll
    for (int e = 0; e < 8; ++e) { w[e] = expf(logit[e] - mx); ssum += w[e]; }
    float inv = 1.0f / ssum;
#pragma unroll
    for (int e = 0; e < 8; ++e) w[e] *= inv;
    float w1v = -1.f, w2v = -1.f; int i1 = 0, i2 = 0;
#pragma unroll
    for (int e = 0; e < 8; ++e) {
      float vv = w[e];
      if (vv > w1v)      { w2v = w1v; i2 = i1; w1v = vv; i1 = e; }
      else if (vv > w2v) { w2v = vv; i2 = e; }
    }
    float s = w1v + w2v;
#pragma unroll
    for (int e = 0; e < 8; ++e) gwout[t * 8 + e] = w[e];
    idxout[t * 2] = (float)i1; idxout[t * 2 + 1] = (float)i2;
    tkwout[t * 2] = w1v / s;   tkwout[t * 2 + 1] = w2v / s;
  }
}

__global__ __launch_bounds__(256) void usage_k(const float* __restrict__ gw,
                                               float* __restrict__ usage) {
  __shared__ float r[256];
  int e = blockIdx.x;
  float s = 0.f;
  for (int t = threadIdx.x; t < N_TOK; t += 256) s += gw[t * 8 + e];
  r[threadIdx.x] = s;
  __syncthreads();
  for (int st = 128; st > 0; st >>= 1) {
    if (threadIdx.x < st) r[threadIdx.x] += r[threadIdx.x + st];
    __syncthreads();
  }
  if (threadIdx.x == 0) usage[e] = r[0] * (1.0f / (float)N_TOK);
}

// ---------------------------------------------------------------------------
// routing (160-row tiles, XCD-clustered block table).  count_hist also
// performs the slot-arena padding init (grid-stride), replacing k_padinit.
// ---------------------------------------------------------------------------
__global__ __launch_bounds__(256) void count_hist(const float* __restrict__ idxout,
                                                  int* __restrict__ blk_cnt,
                                                  int* __restrict__ slot_token,
                                                  float* __restrict__ slot_w) {
  for (int i = blockIdx.x * 256 + threadIdx.x; i < MAX_SLOTS; i += 64 * 256) {
    slot_token[i] = 0;
    slot_w[i] = 0.f;
  }
  __shared__ int h[8];
  if (threadIdx.x < 8) h[threadIdx.x] = 0;
  __syncthreads();
  int t = blockIdx.x * 256 + threadIdx.x;
  int e0 = (int)idxout[t * 2], e1 = (int)idxout[t * 2 + 1];
  atomicAdd(&h[e0], 1);
  atomicAdd(&h[e1], 1);
  __syncthreads();
  if (threadIdx.x < 8) blk_cnt[blockIdx.x * 8 + threadIdx.x] = h[threadIdx.x];
}

__global__ __launch_bounds__(512) void k_offsets2(
    const int* __restrict__ blk_cnt, int* __restrict__ sbase,
    int* __restrict__ blk_e, int* __restrict__ blk_tok0) {
  __shared__ int cnt[64][8];
  __shared__ int ecnt[8];
  __shared__ int offs[8];
  __shared__ int nbtot;
  const int tid = threadIdx.x;
  cnt[tid >> 3][tid & 7] = blk_cnt[tid];
  __syncthreads();
  if (tid < 8) {
    int s = 0;
    for (int b = 0; b < 64; ++b) s += cnt[b][tid];
    ecnt[tid] = s;
  }
  __syncthreads();
  if (tid == 0) {
    int off = 0, nb = 0;
    for (int e = 0; e < 8; ++e) {
      offs[e] = off;
      int nbe = (ecnt[e] + 159) / 160;
      off += nbe * 160;
      nb += nbe;
    }
    nbtot = nb;
  }
  __syncthreads();
  {
    int b = tid >> 3, e = tid & 7;
    int s = offs[e];
    for (int bp = 0; bp < b; ++bp) s += cnt[bp][e];
    sbase[tid] = s;
  }
  const int q = (nbtot + 7) >> 3;
  for (int b = tid; b < MAX_BLOCKS; b += 512) {
    int xcd = b & 7, i = b >> 3;
    int j = xcd * q + i;
    int be = -1, bt = 0;
    if (i < q && j < nbtot) {
      int acc = 0;
#pragma unroll
      for (int e = 0; e < 8; ++e) {
        int nbe = (ecnt[e] + 159) / 160;
        if (j >= acc && j < acc + nbe) { be = e; bt = offs[e] + (j - acc) * 160; }
        acc += nbe;
      }
    }
    blk_e[b] = be;
    blk_tok0[b] = bt;
  }
}

__global__ __launch_bounds__(256) void k_scatter2(
    const float* __restrict__ idxout, const float* __restrict__ tkwout,
    const int* __restrict__ sbase, int* __restrict__ slot_token,
    float* __restrict__ slot_w, int* __restrict__ tok_slot) {
  __shared__ int lpos[8];
  if (threadIdx.x < 8) lpos[threadIdx.x] = 0;
  __syncthreads();
  int t = blockIdx.x * 256 + threadIdx.x;
#pragma unroll
  for (int k = 0; k < 2; ++k) {
    int e = (int)idxout[t * 2 + k];
    int lr = atomicAdd(&lpos[e], 1);
    int s = sbase[blockIdx.x * 8 + e] + lr;
    slot_token[s] = t;
    slot_w[s] = tkwout[t * 2 + k];
    tok_slot[t * 2 + k] = s;
  }
}

// ---------------------------------------------------------------------------
// GEMM3 on 160-row tiles (r13, unchanged)
// ---------------------------------------------------------------------------
__global__ __launch_bounds__(512) void gemm3_eo(
    const u16* __restrict__ h, const u16* __restrict__ w3p,
    const float* __restrict__ b3, const float* __restrict__ slot_w,
    const int* __restrict__ blk_e, const int* __restrict__ blk_tok0,
    float* __restrict__ eo) {
  constexpr int ABYTES = 10240;
  constexpr int BUF = ABYTES + 4096;
  __shared__ char smem[2][BUF];
  int e = blk_e[blockIdx.x];
  if (e < 0) return;
  int row0 = blk_tok0[blockIdx.x];

  const int tid = threadIdx.x;
  const int lane = tid & 63;
  const int wv = tid >> 6;
  const int wm = (wv & 1) * 80;
  const int wn = (wv >> 1) * 16;
  const int l15 = lane & 15, lk = lane >> 4;
  const int swzk16 = (lk ^ ((l15 >> 1) & 3)) << 4;
  const u16* we = w3p + (size_t)e * 32768;

  const int lrq = lane >> 2;
  const int cse = (((lane & 3) ^ ((lane >> 3) & 3)) << 3);
  size_t off[2];
  int ldsoff[2], typ[2];
#pragma unroll
  for (int i = 0; i < 2; ++i) {
    int id = wv + 8 * i;
    if (id >= 14) { typ[i] = 2; off[i] = 0; ldsoff[i] = 0; continue; }
    if (id < 10) {
      off[i] = (size_t)(row0 + id * 16 + lrq) * 512 + cse;
      ldsoff[i] = id * 1024 + lane * 16;
      typ[i] = 0;
    } else {
      int bg = id - 10;
      off[i] = (size_t)bg * 512 + lane * 8;
      ldsoff[i] = ABYTES + bg * 1024 + lane * 16;
      typ[i] = 1;
    }
  }

  auto STAGE = [&](int t, char* b) {
#pragma unroll
    for (int i = 0; i < 2; ++i) {
      if (typ[i] == 0)      gload16(h + off[i] + t * 32, b + ldsoff[i]);
      else if (typ[i] == 1) gload16(we + (size_t)t * 2048 + off[i], b + ldsoff[i]);
    }
  };

  f32x4 acc[5];
#pragma unroll
  for (int j = 0; j < 5; ++j) acc[j] = (f32x4){0.f, 0.f, 0.f, 0.f};

  STAGE(0, smem[0]);
  __syncthreads();
  for (int t = 0; t < 16; ++t) {
    char* cur = smem[t & 1];
    if (t + 1 < 16) STAGE(t + 1, smem[(t + 1) & 1]);
    char* cB = cur + ABYTES;
    bf16x8 bv = *(const bf16x8*)(cB + (wn + l15) * 64 + swzk16);
#pragma unroll
    for (int fm = 0; fm < 5; ++fm) {
      bf16x8 a = *(const bf16x8*)(cur + (wm + fm * 16 + l15) * 64 + swzk16);
      acc[fm] = __builtin_amdgcn_mfma_f32_16x16x32_bf16(a, bv, acc[fm], 0, 0, 0);
    }
    __syncthreads();
  }

#pragma unroll
  for (int fm = 0; fm < 5; ++fm)
#pragma unroll
    for (int r = 0; r < 4; ++r) {
      int row = wm + fm * 16 + lk * 4 + r;
      float w = slot_w[row0 + row];
      int col = wn + l15;
      eo[(size_t)(row0 + row) * 64 + col] = w * (acc[fm][r] + b3[e * 64 + col]);
    }
}

// ---------------------------------------------------------------------------
// combine + final 64x64 projection (unchanged)
// ---------------------------------------------------------------------------
__global__ __launch_bounds__(256) void combine_proj(
    const float* __restrict__ eo, const int* __restrict__ tok_slot,
    const float* __restrict__ pw, const float* __restrict__ pb,
    float* __restrict__ outp) {
  __shared__ float cs[64][68];
  __shared__ float pws[64][68];
  const int t0 = blockIdx.x * 64;
  const int tq = threadIdx.x & 3;
  const int tt = threadIdx.x >> 2;
#pragma unroll
  for (int j = 0; j < 4; ++j) {
    float4 v = *(const float4*)(pw + tt * 64 + tq * 16 + j * 4);
    *(float4*)&pws[tt][tq * 16 + j * 4] = v;
  }
  {
    int t = t0 + tt;
    int s1 = tok_slot[t * 2], s2 = tok_slot[t * 2 + 1];
#pragma unroll
    for (int j = 0; j < 4; ++j) {
      float4 a = *(const float4*)(eo + (size_t)s1 * 64 + tq * 16 + j * 4);
      float4 b = *(const float4*)(eo + (size_t)s2 * 64 + tq * 16 + j * 4);
      float4 c = {a.x + b.x, a.y + b.y, a.z + b.z, a.w + b.w};
      *(float4*)&cs[tt][tq * 16 + j * 4] = c;
    }
  }
  __syncthreads();
  float o[16];
#pragma unroll
  for (int i = 0; i < 16; ++i) o[i] = 0.f;
  for (int j = 0; j < 64; ++j) {
    float c = cs[tt][j];
#pragma unroll
    for (int q4 = 0; q4 < 4; ++q4) {
      float4 p = *(const float4*)&pws[j][tq * 16 + q4 * 4];
      o[q4 * 4 + 0] += c * p.x;
      o[q4 * 4 + 1] += c * p.y;
      o[q4 * 4 + 2] += c * p.z;
      o[q4 * 4 + 3] += c * p.w;
    }
  }
#pragma unroll
  for (int i = 0; i < 16; ++i)
    outp[(size_t)(t0 + tt) * 64 + tq * 16 + i] = o[i] + pb[tq * 16 + i];
}

// ---------------------------------------------------------------------------
extern "C" void kernel_launch(void* const* d_in, const int* in_sizes, int n_in,
                              void* d_out, int out_size, void* d_ws, size_t ws_size,
                              hipStream_t stream) {
  const float* x      = (const float*)d_in[0];
  const float* g_w1   = (const float*)d_in[1];
  const float* g_b1   = (const float*)d_in[2];
  const float* g_lng  = (const float*)d_in[3];
  const float* g_lnb  = (const float*)d_in[4];
  const float* g_w2   = (const float*)d_in[5];
  const float* g_b2   = (const float*)d_in[6];
  const float* e_w1   = (const float*)d_in[7];
  const float* e_b1   = (const float*)d_in[8];
  const float* e_ln1g = (const float*)d_in[9];
  const float* e_ln1b = (const float*)d_in[10];
  const float* e_w2   = (const float*)d_in[11];
  const float* e_b2   = (const float*)d_in[12];
  const float* e_ln2g = (const float*)d_in[13];
  const float* e_ln2b = (const float*)d_in[14];
  const float* e_w3   = (const float*)d_in[15];
  const float* e_b3   = (const float*)d_in[16];
  const float* p_w    = (const float*)d_in[17];
  const float* p_b    = (const float*)d_in[18];

  char* ws = (char*)d_ws;
  u16*   x_bf  = (u16*)(ws);                      // 16 MB
  u16*   x_lo  = (u16*)(ws + (16ull << 20));      // 16 MB
  u16*   e_w1p = (u16*)(ws + (32ull << 20));      // 4 MB
  u16*   e_w2p = (u16*)(ws + (36ull << 20));      // 4 MB
  u16*   e_w3p = (u16*)(ws + (40ull << 20));      // 0.5 MB
  u16*   wcat  = (u16*)(ws + (41ull << 20));      // 1.5 MB
  float* w2t   = (float*)(ws + (43ull << 20));    // 16 KB
  float* gh0   = (float*)(ws + (44ull << 20));    // 44..76 (contiguous w/ gh1)
  float* gh1   = (float*)(ws + (76ull << 20));    // 76..108
  u16*   h     = (u16*)(ws + (44ull << 20));      // overlays after gate
  float* eo    = (float*)(ws + (112ull << 20));   // 112..120.8
  int*   slot_token = (int*)(ws + (121ull << 20));
  float* slot_w     = (float*)(ws + (121ull << 20) + (1ull << 18));
  int*   tok_slot   = (int*)(ws + (121ull << 20) + (2ull << 18));
  int*   blk_cnt    = (int*)(ws + (122ull << 20));
  int*   sbase      = blk_cnt + 512;
  int*   blk_e      = blk_cnt + 1024;
  int*   blk_tok0   = blk_cnt + 2048;
  if (ws_size < (123ull << 20)) return;

  float* fout = (float*)d_out;
  float* o_output = fout;
  float* o_gatew  = fout + 1048576;
  float* o_idx    = fout + 1179648;
  float* o_topw   = fout + 1212416;
  float* o_usage  = fout + 1245184;

  (void)hipFuncSetAttribute((const void*)gemm_core<4, 0, 0, 0, 0>,
                            hipFuncAttributeMaxDynamicSharedMemorySize, 81920);
  (void)hipFuncSetAttribute((const void*)gemm_core<5, 1, 1, 1, 1>,
                            hipFuncAttributeMaxDynamicSharedMemorySize, 86016);
  (void)hipFuncSetAttribute((const void*)gemm_core<5, 1, 0, 1, 1>,
                            hipFuncAttributeMaxDynamicSharedMemorySize, 86016);

  // ---- prep (3 launches) ----
  prep_x<<<8192, 256, 0, stream>>>(x, x_bf, x_lo);
  pack_w_all<<<1088, 256, 0, stream>>>(e_w1, e_w2, e_w3, e_w1p, e_w2p, e_w3p);
  prep_gate_w<<<400, 256, 0, stream>>>(g_w1, wcat, g_w2, w2t);

  // ---- gate: BM=128, split-K (2 halves of 768) -> 256 blocks, 1/CU ----
  gemm_core<4, 0, 0, 0, 0><<<dim3(N_TOK / 128, 2), 512, 81920, stream>>>(
      x_bf, x_lo, wcat, 0, 768, (long)N_TOK * 512, nullptr, 0,
      nullptr, nullptr, nullptr, gh0, nullptr, nullptr, nullptr);
  gate2_topk<<<N_TOK / 4, 256, 0, stream>>>(gh0, gh1, g_b1, g_lng, g_lnb,
                                            w2t, g_b2, o_gatew, o_idx, o_topw);
  usage_k<<<8, 256, 0, stream>>>(o_gatew, o_usage);

  // ---- routing (160-row tiles, XCD-clustered block table) ----
  count_hist<<<64, 256, 0, stream>>>(o_idx, blk_cnt, slot_token, slot_w);
  k_offsets2<<<1, 512, 0, stream>>>(blk_cnt, sbase, blk_e, blk_tok0);
  k_scatter2<<<64, 256, 0, stream>>>(o_idx, o_topw, sbase, slot_token, slot_w,
                                     tok_slot);

  // ---- experts: BM=160, <=212 tiles (tail-free, 1 block/CU) ----
  gemm_core<5, 1, 1, 1, 1><<<MAX_BLOCKS, 512, 86016, stream>>>(
      x_bf, nullptr, e_w1p, 512 * 512, 512, 0, e_b1, 512,
      e_ln1g, e_ln1b, h, nullptr, slot_token, blk_e, blk_tok0);
  gemm_core<5, 1, 0, 1, 1><<<MAX_BLOCKS, 512, 86016, stream>>>(
      h, nullptr, e_w2p, 512 * 512, 512, 0, e_b2, 512,
      e_ln2g, e_ln2b, h, nullptr, slot_token, blk_e, blk_tok0);
  gemm3_eo<<<MAX_BLOCKS, 512, 0, stream>>>(h, e_w3p, e_b3, slot_w, blk_e,
                                           blk_tok0, eo);
  combine_proj<<<N_TOK / 64, 256, 0, stream>>>(eo, tok_slot, p_w, p_b, o_output);
}